// Round 11
// baseline (67.772 us; speedup 1.0000x reference)
//
#include <hip/hip_runtime.h>
#include <hip/hip_bf16.h>

// B=64, N=64, P=128, K=16, M=N*N=4096, T=4096
// Outputs: Z [64,64] then w [64,128,4096], concatenated f32.
//
// Pipeline (3 kernels):
//   K1 k_gemm : blocks 0..1023  : part[tc][k][m] = sum_{256-t-chunk} W^2 G
//               blocks 1024..1087: sbuf[b][k][j] = sum_{p:idx=k} x[b][p][j]
//               block  1088      : rows[k] lists = inverse of idx (LDS-atomic
//                                  counting; list ORDER is nondeterministic but
//                                  w written from it is identical - every row
//                                  of list k gets the same wg[k])
//   K2 k_reduce: wg = sum_tc part ; E = exp(-wg)        (into ws)
//   K3 k_sz   : blocks 0..511   : scatter w[row,:] = wg[k] slice from REGISTERS
//               blocks 512..767 : Z[b][i] = sum_k E[k][i,:] . sbuf[b,k,:]
//
// R5 lesson: no grid-wide fences. R8 lesson: tail (Z) blocks dispatch last.
// R10 lesson: w-write already paces HBM; the lever is killing the gather
// kernel's per-block overheads (mask decode, read side, LDS cap), not cache
// policy.

typedef float f32x4 __attribute__((ext_vector_type(4)));

__device__ __forceinline__ void dma16(const void* g, void* l) {
    __builtin_amdgcn_global_load_lds(
        (const __attribute__((address_space(1))) void*)g,
        (__attribute__((address_space(3))) void*)l, 16, 0, 0);
}

// ---------------------------------------------------------------------------
__global__ __launch_bounds__(256) void k_gemm(const float* __restrict__ W,
                                              const float* __restrict__ G,
                                              float* __restrict__ part,
                                              const float* __restrict__ x,
                                              const float* __restrict__ xmask,
                                              float* __restrict__ sbuf,
                                              int* __restrict__ counts,
                                              int* __restrict__ rows) {
    __shared__ float buf[8192];               // 32 KB
    const int tid = threadIdx.x;
    const int wv  = tid >> 6;
    const int ln  = tid & 63;

    if (blockIdx.x >= 1088) {
        // ---- inverse-index build (1 block) ----
        int* cnt16 = (int*)buf;
        if (tid < 16) cnt16[tid] = 0;
        __syncthreads();
        for (int i = 0; i < 32; ++i) {
            const int bp = tid * 32 + i;
            const float* xm = xmask + (size_t)bp * 16;
            int k = 0;
#pragma unroll
            for (int j = 0; j < 16; ++j) k = (xm[j] > 0.5f) ? j : k;
            const int pos = atomicAdd(&cnt16[k], 1);
            rows[k * 768 + pos] = bp;
        }
        __syncthreads();
        if (tid < 16) counts[tid] = cnt16[tid];
        return;
    }

    if (blockIdx.x >= 1024) {
        // ---- s-accumulation for batch b ----
        const int b = blockIdx.x - 1024;
        float* sw  = buf;                     // [4][16][64] = 16 KB
        int*  idxp = (int*)(buf + 4096);      // 128 ints
        if (tid < 128) {
            const float* xm = xmask + ((size_t)b * 128 + tid) * 16;
            int k = 0;
#pragma unroll
            for (int i = 0; i < 16; ++i) k = (xm[i] > 0.5f) ? i : k;
            idxp[tid] = k;
        }
#pragma unroll
        for (int c = 0; c < 16; ++c) sw[c * 256 + tid] = 0.f;
        __syncthreads();
        const float* xb = x + (size_t)b * 8192;
        for (int p = wv * 32; p < wv * 32 + 32; ++p)
            sw[wv * 1024 + idxp[p] * 64 + ln] += xb[p * 64 + ln];
        __syncthreads();
        for (int e = tid; e < 1024; e += 256)
            sbuf[b * 1024 + e] = sw[e] + sw[1024 + e] + sw[2048 + e] + sw[3072 + e];
        return;
    }

    // ---- GEMM path (unchanged from R9) ----
    float4* w2t4 = (float4*)buf;              // w2t[256][4 quads] = 16 KB
    float4* stg  = (float4*)(buf + 4096);     // 2 stage buffers x 256 f4 = 8 KB

    const int tc  = blockIdx.x & 15;          // t-chunk (256 t each)
    const int mg  = blockIdx.x >> 4;          // m-slice (64 floats)
    const int tt  = tid >> 4;                 // 0..15 t-sublane
    const int t0  = tc * 256;

    {
        float v[16];
#pragma unroll
        for (int k = 0; k < 16; ++k) {
            float w = W[k * 4096 + t0 + tid];
            v[k] = w * w;
        }
#pragma unroll
        for (int q = 0; q < 4; ++q) {
            const int slot = (q + (tid >> 1)) & 3;
            w2t4[tid * 4 + slot] =
                make_float4(v[4*q], v[4*q+1], v[4*q+2], v[4*q+3]);
        }
    }

    const float4* G4 = (const float4*)G;
    const int fi  = wv * 64 + ln;
    const int tl_ = fi >> 4;
    const int mc_ = fi & 15;

    dma16(&G4[(size_t)(t0 + tl_) * 1024 + mg * 16 + mc_], &stg[wv * 64]);
    __syncthreads();

    float4 acc[16];
#pragma unroll
    for (int k = 0; k < 16; ++k) acc[k] = make_float4(0.f, 0.f, 0.f, 0.f);

    for (int s = 0; s < 16; ++s) {
        if (s < 15)
            dma16(&G4[(size_t)(t0 + (s + 1) * 16 + tl_) * 1024 + mg * 16 + mc_],
                  &stg[((s + 1) & 1) * 256 + wv * 64]);

        const float4 g4 = stg[(s & 1) * 256 + tid];
        const int r = s * 16 + tt;
#pragma unroll
        for (int q = 0; q < 4; ++q) {
            const int slot = (q + (r >> 1)) & 3;
            const float4 wq = w2t4[r * 4 + slot];
            const float* wf = (const float*)&wq;
#pragma unroll
            for (int c = 0; c < 4; ++c) {
                const float sc = wf[c];
                acc[q*4+c].x = fmaf(sc, g4.x, acc[q*4+c].x);
                acc[q*4+c].y = fmaf(sc, g4.y, acc[q*4+c].y);
                acc[q*4+c].z = fmaf(sc, g4.z, acc[q*4+c].z);
                acc[q*4+c].w = fmaf(sc, g4.w, acc[q*4+c].w);
            }
        }
        __syncthreads();
    }

    float4* red = (float4*)buf;
    float4* p4  = (float4*)part;
#pragma unroll
    for (int r = 0; r < 2; ++r) {
#pragma unroll
        for (int ks = 0; ks < 8; ++ks)
            red[ks * 256 + tid] = acc[r * 8 + ks];
        __syncthreads();
        if (tid < 128) {
            const int ks = tid >> 4;
            const int c2 = tid & 15;
            float4 s = make_float4(0.f, 0.f, 0.f, 0.f);
#pragma unroll
            for (int t2 = 0; t2 < 16; ++t2) {
                float4 v = red[ks * 256 + t2 * 16 + c2];
                s.x += v.x; s.y += v.y; s.z += v.z; s.w += v.w;
            }
            const int k = r * 8 + ks;
            p4[(size_t)tc * 16384 + (size_t)k * 1024 + mg * 16 + c2] = s;
        }
        __syncthreads();
    }
}

// ---------------------------------------------------------------------------
// grid 256 x 64: thread owns one float4 of wg/E, sums 16 tc partials.
__global__ __launch_bounds__(64) void k_reduce(const float* __restrict__ part,
                                               float* __restrict__ wg,
                                               float* __restrict__ E) {
    const int q = blockIdx.x * 64 + threadIdx.x;     // f4 id 0..16383
    const float4* p4 = (const float4*)part;
    float4 s = make_float4(0.f, 0.f, 0.f, 0.f);
#pragma unroll
    for (int tc = 0; tc < 16; ++tc) {
        float4 v = p4[(size_t)tc * 16384 + q];
        s.x += v.x; s.y += v.y; s.z += v.z; s.w += v.w;
    }
    ((float4*)wg)[q] = s;
    ((float4*)E)[q] = make_float4(expf(-s.x), expf(-s.y), expf(-s.z), expf(-s.w));
}

// ---------------------------------------------------------------------------
// blocks 0..511: scatter. b = (k = b>>5, ms = (b>>3)&3, rh = b&7).
//   slice = wg[k][ms*1024 .. +1024) held one f4/thread; stream-store to each
//   row in this rh-chunk of rows[k].  blocks 512..767: Z.
__global__ __launch_bounds__(256) void k_sz(const int* __restrict__ counts,
                                            const int* __restrict__ rows,
                                            const float* __restrict__ wg,
                                            const float* __restrict__ E,
                                            const float* __restrict__ sbuf,
                                            float* __restrict__ wout,
                                            float* __restrict__ zout) {
    __shared__ int   lrows[128];
    __shared__ float zr[16][16];
    const int tid = threadIdx.x;

    if (blockIdx.x < 512) {
        const int k  = blockIdx.x >> 5;
        const int ms = (blockIdx.x >> 3) & 3;
        const int rh = blockIdx.x & 7;
        const f32x4 v = *(const f32x4*)(wg + (size_t)k * 4096 + ms * 1024 + tid * 4);
        const int cnt   = counts[k];
        const int chunk = (cnt + 7) >> 3;
        const int r0 = rh * chunk;
        const int r1 = (r0 + chunk < cnt) ? (r0 + chunk) : cnt;
        const int n  = r1 - r0;
        if (tid < n) lrows[tid] = rows[k * 768 + r0 + tid];   // chunk <= ~96
        __syncthreads();
        for (int i = 0; i < n; ++i) {
            const int row = lrows[i];
            __builtin_nontemporal_store(
                v, (f32x4*)(wout + (size_t)row * 4096 + ms * 1024 + tid * 4));
        }
        return;
    }

    // ---- Z path ----
    const int zb = blockIdx.x - 512;
    const int b  = zb >> 2;
    const int iq = zb & 3;
    {
        const int k  = tid >> 4;
        const int il = tid & 15;
        const int i  = iq * 16 + il;
        float a = 0.f;
        const float4* Er = (const float4*)(E + (size_t)k * 4096 + i * 64);
        const float4* sr = (const float4*)(sbuf + (size_t)b * 1024 + k * 64);
#pragma unroll
        for (int j4 = 0; j4 < 16; ++j4) {
            float4 e4 = Er[j4];
            float4 s4 = sr[j4];
            a = fmaf(e4.x, s4.x, a);
            a = fmaf(e4.y, s4.y, a);
            a = fmaf(e4.z, s4.z, a);
            a = fmaf(e4.w, s4.w, a);
        }
        zr[k][il] = a;
    }
    __syncthreads();
    if (tid < 16) {
        float s = 0.f;
#pragma unroll
        for (int kk = 0; kk < 16; ++kk) s += zr[kk][tid];
        zout[b * 64 + iq * 16 + tid] = s;
    }
}

extern "C" void kernel_launch(void* const* d_in, const int* in_sizes, int n_in,
                              void* d_out, int out_size, void* d_ws, size_t ws_size,
                              hipStream_t stream) {
    const float* x     = (const float*)d_in[0];   // [64,64,128]
    const float* xmask = (const float*)d_in[1];   // [64,128,16]
    const float* W     = (const float*)d_in[2];   // [16,4096]
    const float* G     = (const float*)d_in[3];   // [4096,4096]

    float* zout = (float*)d_out;                  // [64,64]
    float* wout = (float*)d_out + 4096;           // [64,128,4096]

    float* wg     = (float*)d_ws;                 // 64K f32 (256 KB)
    float* E      = wg + 65536;                   // 64K f32 (256 KB)
    float* sbuf   = E + 65536;                    // 64K f32 (256 KB)
    int*   counts = (int*)(sbuf + 65536);         // 16 ints
    int*   rows   = counts + 16;                  // 16*768 ints (48 KB)

    // partials live in the (dead-until-overwritten) w output region: 4 MB,
    // rows bp 0..1023 — read by k_reduce before k_sz overwrites them.
    float* part = wout;

    k_gemm  <<<1089, 256, 0, stream>>>(W, G, part, x, xmask, sbuf, counts, rows);
    k_reduce<<<256,  64,  0, stream>>>(part, wg, E);
    k_sz    <<<768,  256, 0, stream>>>(counts, rows, wg, E, sbuf, wout, zout);
}

// Round 12
// 64.322 us; speedup vs baseline: 1.0536x; 1.0536x over previous
//
#include <hip/hip_runtime.h>
#include <hip/hip_bf16.h>

// B=64, N=64, P=128, K=16, M=N*N=4096, T=4096
// Outputs: Z [64,64] then w [64,128,4096], concatenated f32.
//
// Pipeline (3 kernels):
//   K1 k_gemm  : part[tc][k][m] = sum_{t in 256-chunk} W[k][t]^2 G[t][m]
//                (R9 structure exactly: DMA double-buffer, pure 1024 blocks —
//                 R11 lesson: no straggler rider blocks in K1)
//   K2 k_reduce: wg = sum_tc part ; E = exp(-wg)
//   K3 k_sz    : blocks 0..255  : scatter — block (b, ms-quarter) stages
//                wg[16][quarter] in LDS (64 KB), decodes b's 128 idx in
//                PARALLEL, then streams 128 x 4 KB NT stores (fill-shaped:
//                linear per-b regions). No per-row decode, no wg re-read.
//                blocks 256..511: Z[b][i] = sum_k E[k][i,:] . s[b,k,:]
//                (self-contained R7 z-path; overlaps the write drain)
// R5 lesson: no grid-wide fences. R10 lesson: cache policy isn't the lever;
// per-block overheads are.

typedef float f32x4 __attribute__((ext_vector_type(4)));

__device__ __forceinline__ void dma16(const void* g, void* l) {
    __builtin_amdgcn_global_load_lds(
        (const __attribute__((address_space(1))) void*)g,
        (__attribute__((address_space(3))) void*)l, 16, 0, 0);
}

// ---------------------------------------------------------------------------
__global__ __launch_bounds__(256) void k_gemm(const float* __restrict__ W,
                                              const float* __restrict__ G,
                                              float* __restrict__ part) {
    __shared__ float buf[8192];               // 32 KB
    float4* w2t4 = (float4*)buf;              // w2t[256][4 quads] = 16 KB
    float4* stg  = (float4*)(buf + 4096);     // 2 stage buffers x 256 f4 = 8 KB

    const int tc  = blockIdx.x & 15;          // t-chunk (256 t each)
    const int mg  = blockIdx.x >> 4;          // m-slice (64 floats)
    const int tid = threadIdx.x;
    const int wv  = tid >> 6;
    const int ln  = tid & 63;
    const int tt  = tid >> 4;                 // 0..15 t-sublane
    const int t0  = tc * 256;

    {
        float v[16];
#pragma unroll
        for (int k = 0; k < 16; ++k) {
            float w = W[k * 4096 + t0 + tid];
            v[k] = w * w;
        }
#pragma unroll
        for (int q = 0; q < 4; ++q) {
            const int slot = (q + (tid >> 1)) & 3;
            w2t4[tid * 4 + slot] =
                make_float4(v[4*q], v[4*q+1], v[4*q+2], v[4*q+3]);
        }
    }

    const float4* G4 = (const float4*)G;
    const int fi  = wv * 64 + ln;
    const int tl_ = fi >> 4;
    const int mc_ = fi & 15;

    dma16(&G4[(size_t)(t0 + tl_) * 1024 + mg * 16 + mc_], &stg[wv * 64]);
    __syncthreads();

    float4 acc[16];
#pragma unroll
    for (int k = 0; k < 16; ++k) acc[k] = make_float4(0.f, 0.f, 0.f, 0.f);

    for (int s = 0; s < 16; ++s) {
        if (s < 15)
            dma16(&G4[(size_t)(t0 + (s + 1) * 16 + tl_) * 1024 + mg * 16 + mc_],
                  &stg[((s + 1) & 1) * 256 + wv * 64]);

        const float4 g4 = stg[(s & 1) * 256 + tid];
        const int r = s * 16 + tt;
#pragma unroll
        for (int q = 0; q < 4; ++q) {
            const int slot = (q + (r >> 1)) & 3;
            const float4 wq = w2t4[r * 4 + slot];
            const float* wf = (const float*)&wq;
#pragma unroll
            for (int c = 0; c < 4; ++c) {
                const float sc = wf[c];
                acc[q*4+c].x = fmaf(sc, g4.x, acc[q*4+c].x);
                acc[q*4+c].y = fmaf(sc, g4.y, acc[q*4+c].y);
                acc[q*4+c].z = fmaf(sc, g4.z, acc[q*4+c].z);
                acc[q*4+c].w = fmaf(sc, g4.w, acc[q*4+c].w);
            }
        }
        __syncthreads();
    }

    float4* red = (float4*)buf;
    float4* p4  = (float4*)part;
#pragma unroll
    for (int r = 0; r < 2; ++r) {
#pragma unroll
        for (int ks = 0; ks < 8; ++ks)
            red[ks * 256 + tid] = acc[r * 8 + ks];
        __syncthreads();
        if (tid < 128) {
            const int ks = tid >> 4;
            const int c2 = tid & 15;
            float4 s = make_float4(0.f, 0.f, 0.f, 0.f);
#pragma unroll
            for (int t2 = 0; t2 < 16; ++t2) {
                float4 v = red[ks * 256 + t2 * 16 + c2];
                s.x += v.x; s.y += v.y; s.z += v.z; s.w += v.w;
            }
            const int k = r * 8 + ks;
            p4[(size_t)tc * 16384 + (size_t)k * 1024 + mg * 16 + c2] = s;
        }
        __syncthreads();
    }
}

// ---------------------------------------------------------------------------
// grid 256 x 64: thread owns one float4 of wg/E, sums 16 tc partials.
__global__ __launch_bounds__(64) void k_reduce(const float* __restrict__ part,
                                               float* __restrict__ wg,
                                               float* __restrict__ E) {
    const int q = blockIdx.x * 64 + threadIdx.x;     // f4 id 0..16383
    const float4* p4 = (const float4*)part;
    float4 s = make_float4(0.f, 0.f, 0.f, 0.f);
#pragma unroll
    for (int tc = 0; tc < 16; ++tc) {
        float4 v = p4[(size_t)tc * 16384 + q];
        s.x += v.x; s.y += v.y; s.z += v.z; s.w += v.w;
    }
    ((float4*)wg)[q] = s;
    ((float4*)E)[q] = make_float4(expf(-s.x), expf(-s.y), expf(-s.z), expf(-s.w));
}

// ---------------------------------------------------------------------------
// blocks 0..255: scatter (b = bid>>2, ms = bid&3).
// blocks 256..511: Z (b = zb>>2, iq = zb&3), self-contained.
__global__ __launch_bounds__(256) void k_sz(const float* __restrict__ x,
                                            const float* __restrict__ xmask,
                                            const float* __restrict__ wg,
                                            const float* __restrict__ E,
                                            float* __restrict__ wout,
                                            float* __restrict__ zout) {
    __shared__ float lds[16512];      // 64.5 KB shared pool (both paths carve)
    const int tid = threadIdx.x;

    if (blockIdx.x < 256) {
        const int b  = blockIdx.x >> 2;
        const int ms = blockIdx.x & 3;
        float4* wgs4 = (float4*)lds;              // 16 k x 256 f4 = 64 KB
        int*    idxl = (int*)(lds + 16384);       // 128 ints

        // parallel idx decode (1 thread per row) — hides under staging
        if (tid < 128) {
            const float* xm = xmask + ((size_t)b * 128 + tid) * 16;
            int k = 0;
#pragma unroll
            for (int j = 0; j < 16; ++j) k = (xm[j] > 0.5f) ? j : k;
            idxl[tid] = k;
        }
        // stage wg[0..16)[ms-quarter] into LDS: e = c*256+tid over 4096 f4
        const float4* wg4 = (const float4*)wg;
#pragma unroll
        for (int c = 0; c < 16; ++c) {
            const int e   = c * 256 + tid;
            const int k   = e >> 8;
            const int off = e & 255;
            wgs4[e] = wg4[(size_t)k * 1024 + ms * 256 + off];
        }
        __syncthreads();

        // stream 128 rows x 4 KB (unrolled x4; independent iterations)
        float* wb = wout + (size_t)b * 128 * 4096 + (size_t)ms * 1024;
        for (int p = 0; p < 128; p += 4) {
            const int k0 = idxl[p + 0];
            const int k1 = idxl[p + 1];
            const int k2 = idxl[p + 2];
            const int k3 = idxl[p + 3];
            f32x4 v0 = ((f32x4*)lds)[k0 * 256 + tid];
            f32x4 v1 = ((f32x4*)lds)[k1 * 256 + tid];
            f32x4 v2 = ((f32x4*)lds)[k2 * 256 + tid];
            f32x4 v3 = ((f32x4*)lds)[k3 * 256 + tid];
            __builtin_nontemporal_store(v0, (f32x4*)(wb + (size_t)(p + 0) * 4096) + tid);
            __builtin_nontemporal_store(v1, (f32x4*)(wb + (size_t)(p + 1) * 4096) + tid);
            __builtin_nontemporal_store(v2, (f32x4*)(wb + (size_t)(p + 2) * 4096) + tid);
            __builtin_nontemporal_store(v3, (f32x4*)(wb + (size_t)(p + 3) * 4096) + tid);
        }
        return;
    }

    // ---- Z path (R7-verified math; LDS carved from pool) ----
    const int zb = blockIdx.x - 256;
    const int b  = zb >> 2;
    const int iq = zb & 3;
    const int wv = tid >> 6;
    const int ln = tid & 63;
    float* sw  = lds;                          // [4][16][64] = 4096 floats
    int*   idx = (int*)(lds + 4096);           // 128 ints
    float* zr  = lds + 4224;                   // [16][16]

    if (tid < 128) {
        const float* xm = xmask + ((size_t)b * 128 + tid) * 16;
        int k = 0;
#pragma unroll
        for (int i = 0; i < 16; ++i) k = (xm[i] > 0.5f) ? i : k;
        idx[tid] = k;
    }
#pragma unroll
    for (int c = 0; c < 16; ++c)
        sw[c * 256 + tid] = 0.f;
    __syncthreads();

    const float* xb = x + (size_t)b * 8192;
    for (int p = wv * 32; p < wv * 32 + 32; ++p) {
        int k = idx[p];
        sw[wv * 1024 + k * 64 + ln] += xb[p * 64 + ln];
    }
    __syncthreads();

    for (int e = tid; e < 1024; e += 256)
        sw[e] = sw[e] + sw[1024 + e] + sw[2048 + e] + sw[3072 + e];
    __syncthreads();

    {
        const int k  = tid >> 4;
        const int il = tid & 15;
        const int i  = iq * 16 + il;
        float a = 0.f;
        const float4* Er = (const float4*)(E + (size_t)k * 4096 + i * 64);
        const float4* sr = (const float4*)(sw + k * 64);
#pragma unroll
        for (int j4 = 0; j4 < 16; ++j4) {
            float4 e4 = Er[j4];
            float4 s4 = sr[j4];
            a = fmaf(e4.x, s4.x, a);
            a = fmaf(e4.y, s4.y, a);
            a = fmaf(e4.z, s4.z, a);
            a = fmaf(e4.w, s4.w, a);
        }
        zr[k * 16 + il] = a;
    }
    __syncthreads();
    if (tid < 16) {
        float s = 0.f;
#pragma unroll
        for (int k = 0; k < 16; ++k) s += zr[k * 16 + tid];
        zout[b * 64 + iq * 16 + tid] = s;
    }
}

extern "C" void kernel_launch(void* const* d_in, const int* in_sizes, int n_in,
                              void* d_out, int out_size, void* d_ws, size_t ws_size,
                              hipStream_t stream) {
    const float* x     = (const float*)d_in[0];   // [64,64,128]
    const float* xmask = (const float*)d_in[1];   // [64,128,16]
    const float* W     = (const float*)d_in[2];   // [16,4096]
    const float* G     = (const float*)d_in[3];   // [4096,4096]

    float* zout = (float*)d_out;                  // [64,64]
    float* wout = (float*)d_out + 4096;           // [64,128,4096]

    float* wg = (float*)d_ws;                     // 64K f32
    float* E  = wg + 65536;                       // 64K f32

    // partials live in the (dead-until-overwritten) w output region: 4 MB,
    // read by k_reduce before k_sz overwrites wout.
    float* part = wout;

    k_gemm  <<<1024, 256, 0, stream>>>(W, G, part);
    k_reduce<<<256,  64,  0, stream>>>(part, wg, E);
    k_sz    <<<512,  256, 0, stream>>>(x, xmask, wg, E, wout, zout);
}

// Round 14
// 48.653 us; speedup vs baseline: 1.3930x; 1.3221x over previous
//
#include <hip/hip_runtime.h>
#include <hip/hip_bf16.h>

// B=64, N=64, P=128, K=16, M=N*N=4096, T=4096
// Outputs: Z [64,64] then w [64,128,4096], concatenated f32.
//
// Pipeline (3 kernels):
//   K1 k_gemm  : part[tc][k][m] = sum_{t in 256-chunk} W[k][t]^2 G[t][m]
//   K2 k_reduce: wg = sum_tc part ; E = exp(-wg)
//   K3 k_wz    : blocks 0..2047  -> w gather, 4 rows/block (ballot decode)
//                blocks 2048..2303 -> Z[b][i] (dispatch LAST: R8 lesson)
// Lessons: R5 no grid-wide fences; R10 cache policy neutral; R11/R12 scatter
// (few blocks, much work) loses to many-small-block gather streams.

typedef float f32x4 __attribute__((ext_vector_type(4)));

__device__ __forceinline__ void dma16(const void* g, void* l) {
    __builtin_amdgcn_global_load_lds(
        (const __attribute__((address_space(1))) void*)g,
        (__attribute__((address_space(3))) void*)l, 16, 0, 0);
}

// ---------------------------------------------------------------------------
__global__ __launch_bounds__(256) void k_gemm(const float* __restrict__ W,
                                              const float* __restrict__ G,
                                              float* __restrict__ part) {
    __shared__ float buf[8192];               // 32 KB
    float4* w2t4 = (float4*)buf;              // w2t[256][4 quads] = 16 KB
    float4* stg  = (float4*)(buf + 4096);     // 2 stage buffers x 256 f4 = 8 KB

    const int tc  = blockIdx.x & 15;          // t-chunk (256 t each)
    const int mg  = blockIdx.x >> 4;          // m-slice (64 floats)
    const int tid = threadIdx.x;
    const int wv  = tid >> 6;
    const int ln  = tid & 63;
    const int tt  = tid >> 4;                 // 0..15 t-sublane
    const int t0  = tc * 256;

    {
        float v[16];
#pragma unroll
        for (int k = 0; k < 16; ++k) {
            float w = W[k * 4096 + t0 + tid];
            v[k] = w * w;
        }
#pragma unroll
        for (int q = 0; q < 4; ++q) {
            const int slot = (q + (tid >> 1)) & 3;
            w2t4[tid * 4 + slot] =
                make_float4(v[4*q], v[4*q+1], v[4*q+2], v[4*q+3]);
        }
    }

    const float4* G4 = (const float4*)G;
    const int fi  = wv * 64 + ln;
    const int tl_ = fi >> 4;
    const int mc_ = fi & 15;

    dma16(&G4[(size_t)(t0 + tl_) * 1024 + mg * 16 + mc_], &stg[wv * 64]);
    __syncthreads();

    float4 acc[16];
#pragma unroll
    for (int k = 0; k < 16; ++k) acc[k] = make_float4(0.f, 0.f, 0.f, 0.f);

    for (int s = 0; s < 16; ++s) {
        if (s < 15)
            dma16(&G4[(size_t)(t0 + (s + 1) * 16 + tl_) * 1024 + mg * 16 + mc_],
                  &stg[((s + 1) & 1) * 256 + wv * 64]);

        const float4 g4 = stg[(s & 1) * 256 + tid];
        const int r = s * 16 + tt;
#pragma unroll
        for (int q = 0; q < 4; ++q) {
            const int slot = (q + (r >> 1)) & 3;
            const float4 wq = w2t4[r * 4 + slot];
            const float* wf = (const float*)&wq;
#pragma unroll
            for (int c = 0; c < 4; ++c) {
                const float sc = wf[c];
                acc[q*4+c].x = fmaf(sc, g4.x, acc[q*4+c].x);
                acc[q*4+c].y = fmaf(sc, g4.y, acc[q*4+c].y);
                acc[q*4+c].z = fmaf(sc, g4.z, acc[q*4+c].z);
                acc[q*4+c].w = fmaf(sc, g4.w, acc[q*4+c].w);
            }
        }
        __syncthreads();
    }

    float4* red = (float4*)buf;
    float4* p4  = (float4*)part;
#pragma unroll
    for (int r = 0; r < 2; ++r) {
#pragma unroll
        for (int ks = 0; ks < 8; ++ks)
            red[ks * 256 + tid] = acc[r * 8 + ks];
        __syncthreads();
        if (tid < 128) {
            const int ks = tid >> 4;
            const int c2 = tid & 15;
            float4 s = make_float4(0.f, 0.f, 0.f, 0.f);
#pragma unroll
            for (int t2 = 0; t2 < 16; ++t2) {
                float4 v = red[ks * 256 + t2 * 16 + c2];
                s.x += v.x; s.y += v.y; s.z += v.z; s.w += v.w;
            }
            const int k = r * 8 + ks;
            p4[(size_t)tc * 16384 + (size_t)k * 1024 + mg * 16 + c2] = s;
        }
        __syncthreads();
    }
}

// ---------------------------------------------------------------------------
// grid 256 x 64: thread owns one float4 of wg/E, sums 16 tc partials.
__global__ __launch_bounds__(64) void k_reduce(const float* __restrict__ part,
                                               float* __restrict__ wg,
                                               float* __restrict__ E) {
    const int q = blockIdx.x * 64 + threadIdx.x;     // f4 id 0..16383
    const float4* p4 = (const float4*)part;
    float4 s = make_float4(0.f, 0.f, 0.f, 0.f);
#pragma unroll
    for (int tc = 0; tc < 16; ++tc) {
        float4 v = p4[(size_t)tc * 16384 + q];
        s.x += v.x; s.y += v.y; s.z += v.z; s.w += v.w;
    }
    ((float4*)wg)[q] = s;
    ((float4*)E)[q] = make_float4(expf(-s.x), expf(-s.y), expf(-s.z), expf(-s.w));
}

// ---------------------------------------------------------------------------
// blocks 0..2047: w gather, 4 rows/block. wave wv ballot-decodes row 4b+wv.
// blocks 2048..2303: Z (b = zb>>2, iq = zb&3).
__global__ __launch_bounds__(256) void k_wz(const float* __restrict__ x,
                                            const float* __restrict__ xmask,
                                            const float* __restrict__ wg,
                                            const float* __restrict__ E,
                                            float* __restrict__ wout,
                                            float* __restrict__ zout) {
    __shared__ float sw[4][16][64];   // 16 KB (z only)
    __shared__ int   idx[128];
    __shared__ float zr[16][16];
    const int tid = threadIdx.x;
    const int wv  = tid >> 6;
    const int ln  = tid & 63;

    if (blockIdx.x < 2048) {
        const int bp0 = blockIdx.x * 4;
        // wave wv decodes mask of row bp0+wv: 1 load + 1 ballot
        const float* xm = xmask + (size_t)(bp0 + wv) * 16;
        float v = (ln < 16) ? xm[ln] : 0.f;
        unsigned long long bal = __ballot(v > 0.5f);
        if (ln == 0) idx[wv] = __ffsll((long long)bal) - 1;
        __syncthreads();
        const int k0 = idx[0], k1 = idx[1], k2 = idx[2], k3 = idx[3];
        const f32x4* s0 = (const f32x4*)(wg + (size_t)k0 * 4096);
        const f32x4* s1 = (const f32x4*)(wg + (size_t)k1 * 4096);
        const f32x4* s2 = (const f32x4*)(wg + (size_t)k2 * 4096);
        const f32x4* s3 = (const f32x4*)(wg + (size_t)k3 * 4096);
        f32x4* d = (f32x4*)(wout + (size_t)bp0 * 4096);
#pragma unroll
        for (int c = 0; c < 4; ++c) {
            const int o = c * 256 + tid;
            d[o]        = s0[o];
            d[1024 + o] = s1[o];
            d[2048 + o] = s2[o];
            d[3072 + o] = s3[o];
        }
        return;
    }

    const int zb = blockIdx.x - 2048;
    const int b  = zb >> 2;
    const int iq = zb & 3;

    if (tid < 128) {
        const float* xm = xmask + ((size_t)b * 128 + tid) * 16;
        int k = 0;
#pragma unroll
        for (int i = 0; i < 16; ++i) k = (xm[i] > 0.5f) ? i : k;
        idx[tid] = k;
    }
#pragma unroll
    for (int c = 0; c < 16; ++c)
        ((float*)sw)[c * 256 + tid] = 0.f;
    __syncthreads();

    // wave wv owns p in [wv*32, wv*32+32); lane = j; x read direct (L2-hot).
    const float* xb = x + (size_t)b * 8192;
    for (int p = wv * 32; p < wv * 32 + 32; ++p) {
        int k = idx[p];
        sw[wv][k][ln] += xb[p * 64 + ln];
    }
    __syncthreads();

    for (int e = tid; e < 1024; e += 256) {
        int k2 = e >> 6, j = e & 63;
        sw[0][k2][j] = sw[0][k2][j] + sw[1][k2][j] + sw[2][k2][j] + sw[3][k2][j];
    }
    __syncthreads();

    {
        const int k  = tid >> 4;
        const int il = tid & 15;
        const int i  = iq * 16 + il;
        float a = 0.f;
        const float4* Er = (const float4*)(E + (size_t)k * 4096 + i * 64);
        const float4* sr = (const float4*)(&sw[0][k][0]);
#pragma unroll
        for (int j4 = 0; j4 < 16; ++j4) {
            float4 e4 = Er[j4];
            float4 s4 = sr[j4];
            a = fmaf(e4.x, s4.x, a);
            a = fmaf(e4.y, s4.y, a);
            a = fmaf(e4.z, s4.z, a);
            a = fmaf(e4.w, s4.w, a);
        }
        zr[k][il] = a;
    }
    __syncthreads();
    if (tid < 16) {
        float s = 0.f;
#pragma unroll
        for (int k = 0; k < 16; ++k) s += zr[k][tid];
        zout[b * 64 + iq * 16 + tid] = s;
    }
}

extern "C" void kernel_launch(void* const* d_in, const int* in_sizes, int n_in,
                              void* d_out, int out_size, void* d_ws, size_t ws_size,
                              hipStream_t stream) {
    const float* x     = (const float*)d_in[0];   // [64,64,128]
    const float* xmask = (const float*)d_in[1];   // [64,128,16]
    const float* W     = (const float*)d_in[2];   // [16,4096]
    const float* G     = (const float*)d_in[3];   // [4096,4096]

    float* zout = (float*)d_out;                  // [64,64]
    float* wout = (float*)d_out + 4096;           // [64,128,4096]

    float* wg = (float*)d_ws;                     // 64K f32
    float* E  = wg + 65536;                       // 64K f32

    // partials live in the (dead-until-overwritten) w output region: 4 MB
    float* part = wout;

    k_gemm  <<<1024, 256, 0, stream>>>(W, G, part);
    k_reduce<<<256,  64,  0, stream>>>(part, wg, E);
    k_wz    <<<2304, 256, 0, stream>>>(x, xmask, wg, E, wout, zout);
}

// Round 15
// 47.193 us; speedup vs baseline: 1.4361x; 1.0309x over previous
//
#include <hip/hip_runtime.h>
#include <hip/hip_bf16.h>

// B=64, N=64, P=128, K=16, M=N*N=4096, T=4096
// Outputs: Z [64,64] then w [64,128,4096], concatenated f32.
//
// Pipeline (3 kernels):
//   K1 k_gemm  : blocks 0..1023   : part[tc][k][m] = sum_{256-t-chunk} W^2 G
//                blocks 1024..1087: sbuf[b][k][j] = sum_{p:idx=k} x[b][p][j]
//                blocks 1088..1119: idxg[row] = argmax(xmask[row]) (1 row/thread
//                                   — R11 lesson: no serial straggler riders)
//   K2 k_reduce: wg = sum_tc part ; E = exp(-wg)
//   K3 k_wz    : blocks 0..2047   : w gather, 4 rows/block, idx precomputed,
//                                   LDS-free, syncthreads-free stream path
//                blocks 2048..2303: Z[b][i] = sum_k E[k][i,:].sbuf[b,k,:] (LAST)
// Lessons: R5 no grid fences; R8 z-last; R10 cache policy neutral; R11/R12
// scatter loses to many-small-block gather; R14 gather is thread-occupancy-
// capped at 4 rows/block.

typedef float f32x4 __attribute__((ext_vector_type(4)));

__device__ __forceinline__ void dma16(const void* g, void* l) {
    __builtin_amdgcn_global_load_lds(
        (const __attribute__((address_space(1))) void*)g,
        (__attribute__((address_space(3))) void*)l, 16, 0, 0);
}

// ---------------------------------------------------------------------------
__global__ __launch_bounds__(256) void k_gemm(const float* __restrict__ W,
                                              const float* __restrict__ G,
                                              float* __restrict__ part,
                                              const float* __restrict__ x,
                                              const float* __restrict__ xmask,
                                              float* __restrict__ sbuf,
                                              int* __restrict__ idxg) {
    __shared__ float buf[8192];               // 32 KB
    const int tid = threadIdx.x;
    const int wv  = tid >> 6;
    const int ln  = tid & 63;

    if (blockIdx.x >= 1088) {
        // ---- idx decode riders: 1 row per thread, fully parallel ----
        const int row = (blockIdx.x - 1088) * 256 + tid;   // 0..8191
        const float* xm = xmask + (size_t)row * 16;
        int k = 0;
#pragma unroll
        for (int j = 0; j < 16; ++j) k = (xm[j] > 0.5f) ? j : k;
        idxg[row] = k;
        return;
    }

    if (blockIdx.x >= 1024) {
        // ---- s-accumulation for batch b (verified R7 code) ----
        const int b = blockIdx.x - 1024;
        float* sw  = buf;                     // [4][16][64] = 16 KB
        int*  idxp = (int*)(buf + 4096);      // 128 ints
        if (tid < 128) {
            const float* xm = xmask + ((size_t)b * 128 + tid) * 16;
            int k = 0;
#pragma unroll
            for (int i = 0; i < 16; ++i) k = (xm[i] > 0.5f) ? i : k;
            idxp[tid] = k;
        }
#pragma unroll
        for (int c = 0; c < 16; ++c) sw[c * 256 + tid] = 0.f;
        __syncthreads();
        const float* xb = x + (size_t)b * 8192;
        for (int p = wv * 32; p < wv * 32 + 32; ++p)
            sw[wv * 1024 + idxp[p] * 64 + ln] += xb[p * 64 + ln];
        __syncthreads();
        for (int e = tid; e < 1024; e += 256)
            sbuf[b * 1024 + e] = sw[e] + sw[1024 + e] + sw[2048 + e] + sw[3072 + e];
        return;
    }

    // ---- GEMM path (unchanged R14) ----
    float4* w2t4 = (float4*)buf;              // w2t[256][4 quads] = 16 KB
    float4* stg  = (float4*)(buf + 4096);     // 2 stage buffers x 256 f4 = 8 KB

    const int tc  = blockIdx.x & 15;          // t-chunk (256 t each)
    const int mg  = blockIdx.x >> 4;          // m-slice (64 floats)
    const int tt  = tid >> 4;                 // 0..15 t-sublane
    const int t0  = tc * 256;

    {
        float v[16];
#pragma unroll
        for (int k = 0; k < 16; ++k) {
            float w = W[k * 4096 + t0 + tid];
            v[k] = w * w;
        }
#pragma unroll
        for (int q = 0; q < 4; ++q) {
            const int slot = (q + (tid >> 1)) & 3;
            w2t4[tid * 4 + slot] =
                make_float4(v[4*q], v[4*q+1], v[4*q+2], v[4*q+3]);
        }
    }

    const float4* G4 = (const float4*)G;
    const int fi  = wv * 64 + ln;
    const int tl_ = fi >> 4;
    const int mc_ = fi & 15;

    dma16(&G4[(size_t)(t0 + tl_) * 1024 + mg * 16 + mc_], &stg[wv * 64]);
    __syncthreads();

    float4 acc[16];
#pragma unroll
    for (int k = 0; k < 16; ++k) acc[k] = make_float4(0.f, 0.f, 0.f, 0.f);

    for (int s = 0; s < 16; ++s) {
        if (s < 15)
            dma16(&G4[(size_t)(t0 + (s + 1) * 16 + tl_) * 1024 + mg * 16 + mc_],
                  &stg[((s + 1) & 1) * 256 + wv * 64]);

        const float4 g4 = stg[(s & 1) * 256 + tid];
        const int r = s * 16 + tt;
#pragma unroll
        for (int q = 0; q < 4; ++q) {
            const int slot = (q + (r >> 1)) & 3;
            const float4 wq = w2t4[r * 4 + slot];
            const float* wf = (const float*)&wq;
#pragma unroll
            for (int c = 0; c < 4; ++c) {
                const float sc = wf[c];
                acc[q*4+c].x = fmaf(sc, g4.x, acc[q*4+c].x);
                acc[q*4+c].y = fmaf(sc, g4.y, acc[q*4+c].y);
                acc[q*4+c].z = fmaf(sc, g4.z, acc[q*4+c].z);
                acc[q*4+c].w = fmaf(sc, g4.w, acc[q*4+c].w);
            }
        }
        __syncthreads();
    }

    float4* red = (float4*)buf;
    float4* p4  = (float4*)part;
#pragma unroll
    for (int r = 0; r < 2; ++r) {
#pragma unroll
        for (int ks = 0; ks < 8; ++ks)
            red[ks * 256 + tid] = acc[r * 8 + ks];
        __syncthreads();
        if (tid < 128) {
            const int ks = tid >> 4;
            const int c2 = tid & 15;
            float4 s = make_float4(0.f, 0.f, 0.f, 0.f);
#pragma unroll
            for (int t2 = 0; t2 < 16; ++t2) {
                float4 v = red[ks * 256 + t2 * 16 + c2];
                s.x += v.x; s.y += v.y; s.z += v.z; s.w += v.w;
            }
            const int k = r * 8 + ks;
            p4[(size_t)tc * 16384 + (size_t)k * 1024 + mg * 16 + c2] = s;
        }
        __syncthreads();
    }
}

// ---------------------------------------------------------------------------
// grid 256 x 64: thread owns one float4 of wg/E, sums 16 tc partials.
__global__ __launch_bounds__(64) void k_reduce(const float* __restrict__ part,
                                               float* __restrict__ wg,
                                               float* __restrict__ E) {
    const int q = blockIdx.x * 64 + threadIdx.x;     // f4 id 0..16383
    const float4* p4 = (const float4*)part;
    float4 s = make_float4(0.f, 0.f, 0.f, 0.f);
#pragma unroll
    for (int tc = 0; tc < 16; ++tc) {
        float4 v = p4[(size_t)tc * 16384 + q];
        s.x += v.x; s.y += v.y; s.z += v.z; s.w += v.w;
    }
    ((float4*)wg)[q] = s;
    ((float4*)E)[q] = make_float4(expf(-s.x), expf(-s.y), expf(-s.z), expf(-s.w));
}

// ---------------------------------------------------------------------------
// blocks 0..2047: w gather, 4 rows/block, precomputed idx, no LDS/sync.
// blocks 2048..2303: Z (b = zb>>2, iq = zb&3) from sbuf (verified R11 path).
__global__ __launch_bounds__(256) void k_wz(const int* __restrict__ idxg,
                                            const float* __restrict__ wg,
                                            const float* __restrict__ E,
                                            const float* __restrict__ sbuf,
                                            float* __restrict__ wout,
                                            float* __restrict__ zout) {
    __shared__ float zr[16][16];      // 1 KB (z path only)
    const int tid = threadIdx.x;

    if (blockIdx.x < 2048) {
        const int bp0 = blockIdx.x * 4;
        const int k0 = idxg[bp0 + 0];
        const int k1 = idxg[bp0 + 1];
        const int k2 = idxg[bp0 + 2];
        const int k3 = idxg[bp0 + 3];
        const f32x4* s0 = (const f32x4*)(wg + (size_t)k0 * 4096);
        const f32x4* s1 = (const f32x4*)(wg + (size_t)k1 * 4096);
        const f32x4* s2 = (const f32x4*)(wg + (size_t)k2 * 4096);
        const f32x4* s3 = (const f32x4*)(wg + (size_t)k3 * 4096);
        f32x4* d = (f32x4*)(wout + (size_t)bp0 * 4096);
#pragma unroll
        for (int c = 0; c < 4; ++c) {
            const int o = c * 256 + tid;
            d[o]        = s0[o];
            d[1024 + o] = s1[o];
            d[2048 + o] = s2[o];
            d[3072 + o] = s3[o];
        }
        return;
    }

    // ---- Z path (verified R11/R12 form) ----
    const int zb = blockIdx.x - 2048;
    const int b  = zb >> 2;
    const int iq = zb & 3;
    {
        const int k  = tid >> 4;
        const int il = tid & 15;
        const int i  = iq * 16 + il;
        float a = 0.f;
        const float4* Er = (const float4*)(E + (size_t)k * 4096 + i * 64);
        const float4* sr = (const float4*)(sbuf + (size_t)b * 1024 + k * 64);
#pragma unroll
        for (int j4 = 0; j4 < 16; ++j4) {
            float4 e4 = Er[j4];
            float4 s4 = sr[j4];
            a = fmaf(e4.x, s4.x, a);
            a = fmaf(e4.y, s4.y, a);
            a = fmaf(e4.z, s4.z, a);
            a = fmaf(e4.w, s4.w, a);
        }
        zr[k][il] = a;
    }
    __syncthreads();
    if (tid < 16) {
        float s = 0.f;
#pragma unroll
        for (int kk = 0; kk < 16; ++kk) s += zr[kk][tid];
        zout[b * 64 + iq * 16 + tid] = s;
    }
}

extern "C" void kernel_launch(void* const* d_in, const int* in_sizes, int n_in,
                              void* d_out, int out_size, void* d_ws, size_t ws_size,
                              hipStream_t stream) {
    const float* x     = (const float*)d_in[0];   // [64,64,128]
    const float* xmask = (const float*)d_in[1];   // [64,128,16]
    const float* W     = (const float*)d_in[2];   // [16,4096]
    const float* G     = (const float*)d_in[3];   // [4096,4096]

    float* zout = (float*)d_out;                  // [64,64]
    float* wout = (float*)d_out + 4096;           // [64,128,4096]

    float* wg   = (float*)d_ws;                   // 64K f32 (256 KB)
    float* E    = wg + 65536;                     // 64K f32 (256 KB)
    float* sbuf = E + 65536;                      // 64K f32 (256 KB)
    int*   idxg = (int*)(sbuf + 65536);           // 8192 ints (32 KB)

    // partials live in the (dead-until-overwritten) w output region: 4 MB
    float* part = wout;

    k_gemm  <<<1120, 256, 0, stream>>>(W, G, part, x, xmask, sbuf, idxg);
    k_reduce<<<256,  64,  0, stream>>>(part, wg, E);
    k_wz    <<<2304, 256, 0, stream>>>(idxg, wg, E, sbuf, wout, zout);
}

// Round 16
// 46.105 us; speedup vs baseline: 1.4699x; 1.0236x over previous
//
#include <hip/hip_runtime.h>
#include <hip/hip_bf16.h>

// B=64, N=64, P=128, K=16, M=N*N=4096, T=4096
// Outputs: Z [64,64] then w [64,128,4096], concatenated f32.
//
// Pipeline (3 kernels):
//   K1 k_gemm  : blocks 0..1023   : part[tc][k][m] = sum_{256-t-chunk} W^2 G
//                XCD-swizzled: XCD x owns tc{2x,2x+1} -> G rows L2-shared 64x
//                blocks 1024..1087: sbuf[b][k][j] = sum_{p:idx=k} x[b][p][j]
//                blocks 1088..1119: idxg[row] = argmax(xmask[row])
//   K2 k_reduce: wg = sum_tc part ; E = exp(-wg)
//   K3 k_wz    : blocks 0..2047   : w gather, 4 rows/block, idx precomputed
//                blocks 2048..2303: Z[b][i] = sum_k E[k][i,:].sbuf[b,k,:]
// Lessons: R5 no grid fences; R8 z-last; R10 cache policy neutral; R11/R12
// scatter loses to many-small-block gather; R14 gather thread-capped at 4
// rows/block; R15 riders under gemm are free.

typedef float f32x4 __attribute__((ext_vector_type(4)));

__device__ __forceinline__ void dma16(const void* g, void* l) {
    __builtin_amdgcn_global_load_lds(
        (const __attribute__((address_space(1))) void*)g,
        (__attribute__((address_space(3))) void*)l, 16, 0, 0);
}

// ---------------------------------------------------------------------------
__global__ __launch_bounds__(256) void k_gemm(const float* __restrict__ W,
                                              const float* __restrict__ G,
                                              float* __restrict__ part,
                                              const float* __restrict__ x,
                                              const float* __restrict__ xmask,
                                              float* __restrict__ sbuf,
                                              int* __restrict__ idxg) {
    __shared__ float buf[8192];               // 32 KB
    const int tid = threadIdx.x;
    const int wv  = tid >> 6;
    const int ln  = tid & 63;

    if (blockIdx.x >= 1088) {
        // ---- idx decode riders: 1 row per thread, fully parallel ----
        const int row = (blockIdx.x - 1088) * 256 + tid;   // 0..8191
        const float* xm = xmask + (size_t)row * 16;
        int k = 0;
#pragma unroll
        for (int j = 0; j < 16; ++j) k = (xm[j] > 0.5f) ? j : k;
        idxg[row] = k;
        return;
    }

    if (blockIdx.x >= 1024) {
        // ---- s-accumulation for batch b (verified R7 code) ----
        const int b = blockIdx.x - 1024;
        float* sw  = buf;                     // [4][16][64] = 16 KB
        int*  idxp = (int*)(buf + 4096);      // 128 ints
        if (tid < 128) {
            const float* xm = xmask + ((size_t)b * 128 + tid) * 16;
            int k = 0;
#pragma unroll
            for (int i = 0; i < 16; ++i) k = (xm[i] > 0.5f) ? i : k;
            idxp[tid] = k;
        }
#pragma unroll
        for (int c = 0; c < 16; ++c) sw[c * 256 + tid] = 0.f;
        __syncthreads();
        const float* xb = x + (size_t)b * 8192;
        for (int p = wv * 32; p < wv * 32 + 32; ++p)
            sw[wv * 1024 + idxp[p] * 64 + ln] += xb[p * 64 + ln];
        __syncthreads();
        for (int e = tid; e < 1024; e += 256)
            sbuf[b * 1024 + e] = sw[e] + sw[1024 + e] + sw[2048 + e] + sw[3072 + e];
        return;
    }

    // ---- GEMM path ----
    float4* w2t4 = (float4*)buf;              // w2t[256][4 quads] = 16 KB
    float4* stg  = (float4*)(buf + 4096);     // 2 stage buffers x 256 f4 = 8 KB

    // XCD-aware swizzle (R16): dispatch round-robins XCD = blockIdx%8.
    // Give XCD x the tc pair {2x,2x+1} so its 128 blocks share an 8 MB
    // G window inside one L2 (64-way line reuse) instead of streaming
    // the full 64 MB through every XCD's L2.
    const int xcd = blockIdx.x & 7;
    const int j   = blockIdx.x >> 3;          // 0..127
    const int tc  = 2 * xcd + (j >> 6);       // t-chunk (256 t each)
    const int mg  = j & 63;                   // m-slice (64 floats)
    const int tt  = tid >> 4;                 // 0..15 t-sublane
    const int t0  = tc * 256;

    {
        float v[16];
#pragma unroll
        for (int k = 0; k < 16; ++k) {
            float w = W[k * 4096 + t0 + tid];
            v[k] = w * w;
        }
#pragma unroll
        for (int q = 0; q < 4; ++q) {
            const int slot = (q + (tid >> 1)) & 3;
            w2t4[tid * 4 + slot] =
                make_float4(v[4*q], v[4*q+1], v[4*q+2], v[4*q+3]);
        }
    }

    const float4* G4 = (const float4*)G;
    const int fi  = wv * 64 + ln;
    const int tl_ = fi >> 4;
    const int mc_ = fi & 15;

    dma16(&G4[(size_t)(t0 + tl_) * 1024 + mg * 16 + mc_], &stg[wv * 64]);
    __syncthreads();

    float4 acc[16];
#pragma unroll
    for (int k = 0; k < 16; ++k) acc[k] = make_float4(0.f, 0.f, 0.f, 0.f);

    for (int s = 0; s < 16; ++s) {
        if (s < 15)
            dma16(&G4[(size_t)(t0 + (s + 1) * 16 + tl_) * 1024 + mg * 16 + mc_],
                  &stg[((s + 1) & 1) * 256 + wv * 64]);

        const float4 g4 = stg[(s & 1) * 256 + tid];
        const int r = s * 16 + tt;
#pragma unroll
        for (int q = 0; q < 4; ++q) {
            const int slot = (q + (r >> 1)) & 3;
            const float4 wq = w2t4[r * 4 + slot];
            const float* wf = (const float*)&wq;
#pragma unroll
            for (int c = 0; c < 4; ++c) {
                const float sc = wf[c];
                acc[q*4+c].x = fmaf(sc, g4.x, acc[q*4+c].x);
                acc[q*4+c].y = fmaf(sc, g4.y, acc[q*4+c].y);
                acc[q*4+c].z = fmaf(sc, g4.z, acc[q*4+c].z);
                acc[q*4+c].w = fmaf(sc, g4.w, acc[q*4+c].w);
            }
        }
        __syncthreads();
    }

    float4* red = (float4*)buf;
    float4* p4  = (float4*)part;
#pragma unroll
    for (int r = 0; r < 2; ++r) {
#pragma unroll
        for (int ks = 0; ks < 8; ++ks)
            red[ks * 256 + tid] = acc[r * 8 + ks];
        __syncthreads();
        if (tid < 128) {
            const int ks = tid >> 4;
            const int c2 = tid & 15;
            float4 s = make_float4(0.f, 0.f, 0.f, 0.f);
#pragma unroll
            for (int t2 = 0; t2 < 16; ++t2) {
                float4 v = red[ks * 256 + t2 * 16 + c2];
                s.x += v.x; s.y += v.y; s.z += v.z; s.w += v.w;
            }
            const int k = r * 8 + ks;
            p4[(size_t)tc * 16384 + (size_t)k * 1024 + mg * 16 + c2] = s;
        }
        __syncthreads();
    }
}

// ---------------------------------------------------------------------------
// grid 256 x 64: thread owns one float4 of wg/E, sums 16 tc partials.
__global__ __launch_bounds__(64) void k_reduce(const float* __restrict__ part,
                                               float* __restrict__ wg,
                                               float* __restrict__ E) {
    const int q = blockIdx.x * 64 + threadIdx.x;     // f4 id 0..16383
    const float4* p4 = (const float4*)part;
    float4 s = make_float4(0.f, 0.f, 0.f, 0.f);
#pragma unroll
    for (int tc = 0; tc < 16; ++tc) {
        float4 v = p4[(size_t)tc * 16384 + q];
        s.x += v.x; s.y += v.y; s.z += v.z; s.w += v.w;
    }
    ((float4*)wg)[q] = s;
    ((float4*)E)[q] = make_float4(expf(-s.x), expf(-s.y), expf(-s.z), expf(-s.w));
}

// ---------------------------------------------------------------------------
// blocks 0..2047: w gather, 4 rows/block, precomputed idx, no LDS/sync.
// blocks 2048..2303: Z (b = zb>>2, iq = zb&3) from sbuf.
__global__ __launch_bounds__(256) void k_wz(const int* __restrict__ idxg,
                                            const float* __restrict__ wg,
                                            const float* __restrict__ E,
                                            const float* __restrict__ sbuf,
                                            float* __restrict__ wout,
                                            float* __restrict__ zout) {
    __shared__ float zr[16][16];      // 1 KB (z path only)
    const int tid = threadIdx.x;

    if (blockIdx.x < 2048) {
        const int bp0 = blockIdx.x * 4;
        const int k0 = idxg[bp0 + 0];
        const int k1 = idxg[bp0 + 1];
        const int k2 = idxg[bp0 + 2];
        const int k3 = idxg[bp0 + 3];
        const f32x4* s0 = (const f32x4*)(wg + (size_t)k0 * 4096);
        const f32x4* s1 = (const f32x4*)(wg + (size_t)k1 * 4096);
        const f32x4* s2 = (const f32x4*)(wg + (size_t)k2 * 4096);
        const f32x4* s3 = (const f32x4*)(wg + (size_t)k3 * 4096);
        f32x4* d = (f32x4*)(wout + (size_t)bp0 * 4096);
#pragma unroll
        for (int c = 0; c < 4; ++c) {
            const int o = c * 256 + tid;
            d[o]        = s0[o];
            d[1024 + o] = s1[o];
            d[2048 + o] = s2[o];
            d[3072 + o] = s3[o];
        }
        return;
    }

    // ---- Z path ----
    const int zb = blockIdx.x - 2048;
    const int b  = zb >> 2;
    const int iq = zb & 3;
    {
        const int k  = tid >> 4;
        const int il = tid & 15;
        const int i  = iq * 16 + il;
        float a = 0.f;
        const float4* Er = (const float4*)(E + (size_t)k * 4096 + i * 64);
        const float4* sr = (const float4*)(sbuf + (size_t)b * 1024 + k * 64);
#pragma unroll
        for (int j4 = 0; j4 < 16; ++j4) {
            float4 e4 = Er[j4];
            float4 s4 = sr[j4];
            a = fmaf(e4.x, s4.x, a);
            a = fmaf(e4.y, s4.y, a);
            a = fmaf(e4.z, s4.z, a);
            a = fmaf(e4.w, s4.w, a);
        }
        zr[k][il] = a;
    }
    __syncthreads();
    if (tid < 16) {
        float s = 0.f;
#pragma unroll
        for (int kk = 0; kk < 16; ++kk) s += zr[kk][tid];
        zout[b * 64 + iq * 16 + tid] = s;
    }
}

extern "C" void kernel_launch(void* const* d_in, const int* in_sizes, int n_in,
                              void* d_out, int out_size, void* d_ws, size_t ws_size,
                              hipStream_t stream) {
    const float* x     = (const float*)d_in[0];   // [64,64,128]
    const float* xmask = (const float*)d_in[1];   // [64,128,16]
    const float* W     = (const float*)d_in[2];   // [16,4096]
    const float* G     = (const float*)d_in[3];   // [4096,4096]

    float* zout = (float*)d_out;                  // [64,64]
    float* wout = (float*)d_out + 4096;           // [64,128,4096]

    float* wg   = (float*)d_ws;                   // 64K f32 (256 KB)
    float* E    = wg + 65536;                     // 64K f32 (256 KB)
    float* sbuf = E + 65536;                      // 64K f32 (256 KB)
    int*   idxg = (int*)(sbuf + 65536);           // 8192 ints (32 KB)

    // partials live in the (dead-until-overwritten) w output region: 4 MB
    float* part = wout;

    k_gemm  <<<1120, 256, 0, stream>>>(W, G, part, x, xmask, sbuf, idxg);
    k_reduce<<<256,  64,  0, stream>>>(part, wg, E);
    k_wz    <<<2304, 256, 0, stream>>>(idxg, wg, E, sbuf, wout, zout);
}